// Round 1
// 912.804 us; speedup vs baseline: 1.2960x; 1.2960x over previous
//
#include <hip/hip_runtime.h>
#include <math.h>

#define FDIM 64
#define HDIM 128

typedef __attribute__((ext_vector_type(8)))  short v8s;
typedef __attribute__((ext_vector_type(16))) float f32x16;

#define MFMA32(a,b,c) __builtin_amdgcn_mfma_f32_32x32x16_bf16(a,b,c,0,0,0)

// ---- fp32 -> bf16 hi/lo split helpers (hi = truncation, lo = round-half-up of exact remainder)
__device__ __forceinline__ unsigned short bf_hi(float v){
    return (unsigned short)(__float_as_uint(v) >> 16);
}
__device__ __forceinline__ float hi_part(float v){
    return __uint_as_float(__float_as_uint(v) & 0xFFFF0000u);
}
__device__ __forceinline__ unsigned short bf_rnd(float v){
    return (unsigned short)((__float_as_uint(v) + 0x8000u) >> 16);
}

// ---- branchless gelu: 0.5x(1+erf(x/sqrt2)), erf via A&S 7.1.26 (|err|<1.5e-7), tail clamped at z=4
__device__ __forceinline__ float gelu_fast(float x){
    float z = fminf(fabsf(x) * 0.70710678118654752440f, 4.0f);
    float t = __builtin_amdgcn_rcpf(fmaf(0.3275911f, z, 1.0f));
    float p = fmaf(t, 1.061405429f, -1.453152027f);
    p = fmaf(t, p, 1.421413741f);
    p = fmaf(t, p, -0.284496736f);
    p = fmaf(t, p, 0.254829592f);
    float r  = t * p;
    float ez = __expf(-z * z);
    float erfv = fmaf(-r, ez, 1.0f);      // 1 - R*e^{-z^2}
    erfv = copysignf(erfv, x);
    float hx = 0.5f * x;
    return fmaf(hx, erfv, hx);
}

// =====================================================================================
// Prep kernel: split W1..W4 into hi/lo bf16, stored in MFMA B-fragment order.
// Fragment for tile (nt,ks): lane l holds B[k][n], k = ks*16 + (l>>5)*8 + j, n = nt*32 + (l&31).
// ws layout (u16): W1 @0 (16 tiles), W2 @16384 (16), W3 @32768 (16), W4 @49152 (32);
// each tile = 1024 u16: [0,512) hi frags (lane*8+j), [512,1024) lo frags. Total 163840 B.
// =====================================================================================
__global__ void prep_w(const float* __restrict__ W1, const float* __restrict__ W2,
                       const float* __restrict__ W3, const float* __restrict__ W4,
                       unsigned short* __restrict__ wf)
{
    int idx = blockIdx.x * 256 + threadIdx.x;
    if (idx >= 40960) return;
    const float* W; int N, KS, ub, local;
    if (idx < 8192)       { W = W1; N = HDIM; KS = 4; ub = 0;     local = idx;         }
    else if (idx < 16384) { W = W2; N = FDIM; KS = 8; ub = 16384; local = idx - 8192;  }
    else if (idx < 24576) { W = W3; N = HDIM; KS = 4; ub = 32768; local = idx - 16384; }
    else                  { W = W4; N = HDIM; KS = 8; ub = 49152; local = idx - 24576; }
    int tile   = local >> 9;
    int within = local & 511;
    int l = within >> 3, j = within & 7;
    int ks = tile % KS, nt = tile / KS;
    int k = ks * 16 + (l >> 5) * 8 + j;
    int n = nt * 32 + (l & 31);
    float v = W[k * N + n];
    float rem = v - hi_part(v);
    wf[ub + tile * 1024 +       l * 8 + j] = bf_hi(v);
    wf[ub + tile * 1024 + 512 + l * 8 + j] = bf_rnd(rem);
}

// =====================================================================================
// Main kernel: 1 wave = 32 edges. 2 waves/block. All 4 GEMMs via 32x32x16 bf16 MFMA,
// 3-term hi/lo split. Activations in wave-private XOR-swizzled bf16 LDS (no barriers).
// Per-wave LDS: R64 hi/lo (2x4096) + R128 hi/lo (2x8192) + idx (384) = 24960 B.
// =====================================================================================
#define R64H  0
#define R64L  4096
#define R128H 8192
#define R128L 16384
#define IDXB  24576
#define WLDS  24960

__global__ __launch_bounds__(128, 2)
void arn_mfma(const float* __restrict__ known_mask,
              const int*   __restrict__ obs_idx,
              const int*   __restrict__ obs_mask_idx,
              const int*   __restrict__ attr_idx,
              const float* __restrict__ obs_embs,
              const float* __restrict__ fea_corr,
              const float* __restrict__ b_rm1, const float* __restrict__ b_rm2,
              const float* __restrict__ b_rr,  const float* __restrict__ b_rc,
              const unsigned short* __restrict__ wf,
              float* __restrict__ out, int E)
{
    __shared__ __align__(16) unsigned char smem_all[2 * WLDS];
    const int wave = threadIdx.x >> 6;
    const int lane = threadIdx.x & 63;
    unsigned char* smem = smem_all + wave * WLDS;
    const long long ebase = ((long long)blockIdx.x * 2 + wave) * 32;

    int* sAttr = (int*)(smem + IDXB);
    int* sObs  = sAttr + 32;
    int* sMrow = sAttr + 64;

    const int cl = lane & 31;   // A-row / B-col / C-col within 32-tile
    const int hf = lane >> 5;   // k-half selector

    // ---- indices for this wave's 32 edges (same-wave DS ops are in-order; no barrier needed)
    if (lane < 32){
        long long e = ebase + lane;
        int ec = (e < (long long)E) ? (int)e : (E - 1);
        sAttr[lane] = attr_idx[ec];
        sObs[lane]  = obs_idx[ec];
        sMrow[lane] = obs_mask_idx[ec];
    }

    // ---- stage 0: gather mask row, self-mask, softmax -> S (bf16 hi/lo) into R64
    #pragma unroll 1
    for (int r = 0; r < 32; ++r){
        int attr = sAttr[r];
        int mrow = sMrow[r];
        float v = known_mask[(long long)mrow * FDIM + lane];
        if (lane == attr) v = 0.f;
        float mx = v;
        #pragma unroll
        for (int off = 32; off; off >>= 1) mx = fmaxf(mx, __shfl_xor(mx, off));
        float ex = __expf(v - mx);
        float s = ex;
        #pragma unroll
        for (int off = 32; off; off >>= 1) s += __shfl_xor(s, off);
        float val = ex * __builtin_amdgcn_rcpf(s);
        int off64 = r * 128 + ((lane * 2) ^ ((r & 7) << 4));
        *(unsigned short*)(smem + R64H + off64) = bf_hi(val);
        *(unsigned short*)(smem + R64L + off64) = bf_rnd(val - hi_part(val));
    }

    // ---- GEMM1: S[32,64] @ W_rm1[64,128] -> gelu -> h1 (R128)
    {
        v8s ah[4], al[4];
        #pragma unroll
        for (int ks = 0; ks < 4; ++ks){
            int off = cl * 128 + ((ks * 32 + hf * 16) ^ ((cl & 7) << 4));
            ah[ks] = *(const v8s*)(smem + R64H + off);
            al[ks] = *(const v8s*)(smem + R64L + off);
        }
        #pragma unroll
        for (int nt = 0; nt < 4; ++nt){
            float bias = b_rm1[nt * 32 + cl];
            f32x16 acc;
            #pragma unroll
            for (int i = 0; i < 16; ++i) acc[i] = bias;
            #pragma unroll
            for (int ks = 0; ks < 4; ++ks){
                const v8s* wp = (const v8s*)(wf + (nt * 4 + ks) * 1024);
                v8s bh = wp[lane], bl = wp[lane + 64];
                acc = MFMA32(ah[ks], bh, acc);
                acc = MFMA32(ah[ks], bl, acc);
                acc = MFMA32(al[ks], bh, acc);
            }
            #pragma unroll
            for (int g = 0; g < 16; ++g){
                int row = (g & 3) + 8 * (g >> 2) + 4 * hf;
                float y = gelu_fast(acc[g]);
                int off = row * 256 + (((nt * 32 + cl) * 2) ^ ((row & 7) << 4));
                *(unsigned short*)(smem + R128H + off) = bf_hi(y);
                *(unsigned short*)(smem + R128L + off) = bf_rnd(y - hi_part(y));
            }
        }
    }

    // ---- GEMM2: h1[32,128] @ W_rm2[128,64] -> gelu -> * fea_corr[attr] -> t (R64)
    {
        v8s ah[8], al[8];
        #pragma unroll
        for (int ks = 0; ks < 8; ++ks){
            int off = cl * 256 + ((ks * 32 + hf * 16) ^ ((cl & 7) << 4));
            ah[ks] = *(const v8s*)(smem + R128H + off);
            al[ks] = *(const v8s*)(smem + R128L + off);
        }
        int ai[16];
        #pragma unroll
        for (int g = 0; g < 16; ++g){
            int row = (g & 3) + 8 * (g >> 2) + 4 * hf;
            ai[g] = sAttr[row];
        }
        #pragma unroll
        for (int nt = 0; nt < 2; ++nt){
            float bias = b_rm2[nt * 32 + cl];
            f32x16 acc;
            #pragma unroll
            for (int i = 0; i < 16; ++i) acc[i] = bias;
            #pragma unroll
            for (int ks = 0; ks < 8; ++ks){
                const v8s* wp = (const v8s*)(wf + 16384 + (nt * 8 + ks) * 1024);
                v8s bh = wp[lane], bl = wp[lane + 64];
                acc = MFMA32(ah[ks], bh, acc);
                acc = MFMA32(ah[ks], bl, acc);
                acc = MFMA32(al[ks], bh, acc);
            }
            #pragma unroll
            for (int g = 0; g < 16; ++g){
                int row = (g & 3) + 8 * (g >> 2) + 4 * hf;
                float fc = fea_corr[ai[g] * FDIM + nt * 32 + cl];
                float y = gelu_fast(acc[g]) * fc;
                int off = row * 128 + (((nt * 32 + cl) * 2) ^ ((row & 7) << 4));
                *(unsigned short*)(smem + R64H + off) = bf_hi(y);
                *(unsigned short*)(smem + R64L + off) = bf_rnd(y - hi_part(y));
            }
        }
    }

    // ---- GEMM3: t[32,64] @ W_rr[64,128] -> gelu -> * obs_h -> u (R128)
    {
        v8s ah[4], al[4];
        #pragma unroll
        for (int ks = 0; ks < 4; ++ks){
            int off = cl * 128 + ((ks * 32 + hf * 16) ^ ((cl & 7) << 4));
            ah[ks] = *(const v8s*)(smem + R64H + off);
            al[ks] = *(const v8s*)(smem + R64L + off);
        }
        int oi[16];
        #pragma unroll
        for (int g = 0; g < 16; ++g){
            int row = (g & 3) + 8 * (g >> 2) + 4 * hf;
            oi[g] = sObs[row];
        }
        // prefetch obs gather values (hides L3 latency under the MFMA block)
        float obsv[4][16];
        #pragma unroll
        for (int nt = 0; nt < 4; ++nt){
            #pragma unroll
            for (int g = 0; g < 16; ++g)
                obsv[nt][g] = obs_embs[(long long)oi[g] * HDIM + nt * 32 + cl];
        }
        #pragma unroll
        for (int nt = 0; nt < 4; ++nt){
            float bias = b_rr[nt * 32 + cl];
            f32x16 acc;
            #pragma unroll
            for (int i = 0; i < 16; ++i) acc[i] = bias;
            #pragma unroll
            for (int ks = 0; ks < 4; ++ks){
                const v8s* wp = (const v8s*)(wf + 32768 + (nt * 4 + ks) * 1024);
                v8s bh = wp[lane], bl = wp[lane + 64];
                acc = MFMA32(ah[ks], bh, acc);
                acc = MFMA32(ah[ks], bl, acc);
                acc = MFMA32(al[ks], bh, acc);
            }
            #pragma unroll
            for (int g = 0; g < 16; ++g){
                int row = (g & 3) + 8 * (g >> 2) + 4 * hf;
                float y = obsv[nt][g] * gelu_fast(acc[g]);
                int off = row * 256 + (((nt * 32 + cl) * 2) ^ ((row & 7) << 4));
                *(unsigned short*)(smem + R128H + off) = bf_hi(y);
                *(unsigned short*)(smem + R128L + off) = bf_rnd(y - hi_part(y));
            }
        }
    }

    // ---- GEMM4: u[32,128] @ W_rc[128,128] -> gelu -> out
    {
        v8s ah[8], al[8];
        #pragma unroll
        for (int ks = 0; ks < 8; ++ks){
            int off = cl * 256 + ((ks * 32 + hf * 16) ^ ((cl & 7) << 4));
            ah[ks] = *(const v8s*)(smem + R128H + off);
            al[ks] = *(const v8s*)(smem + R128L + off);
        }
        #pragma unroll
        for (int nt = 0; nt < 4; ++nt){
            float bias = b_rc[nt * 32 + cl];
            f32x16 acc;
            #pragma unroll
            for (int i = 0; i < 16; ++i) acc[i] = bias;
            #pragma unroll
            for (int ks = 0; ks < 8; ++ks){
                const v8s* wp = (const v8s*)(wf + 49152 + (nt * 8 + ks) * 1024);
                v8s bh = wp[lane], bl = wp[lane + 64];
                acc = MFMA32(ah[ks], bh, acc);
                acc = MFMA32(ah[ks], bl, acc);
                acc = MFMA32(al[ks], bh, acc);
            }
            #pragma unroll
            for (int g = 0; g < 16; ++g){
                int row = (g & 3) + 8 * (g >> 2) + 4 * hf;
                long long e = ebase + row;
                if (e < (long long)E)
                    out[e * HDIM + nt * 32 + cl] = gelu_fast(acc[g]);
            }
        }
    }
}

extern "C" void kernel_launch(void* const* d_in, const int* in_sizes, int n_in,
                              void* d_out, int out_size, void* d_ws, size_t ws_size,
                              hipStream_t stream)
{
    (void)n_in; (void)out_size; (void)ws_size;   // requires ws_size >= 163840 B
    const float* known_mask   = (const float*)d_in[0];
    const int*   obs_idx      = (const int*)d_in[1];
    const int*   obs_mask_idx = (const int*)d_in[2];
    const int*   attr_idx     = (const int*)d_in[3];
    const float* obs_embs     = (const float*)d_in[4];
    const float* fea_corr     = (const float*)d_in[5];
    const float* W_rm1 = (const float*)d_in[6];
    const float* b_rm1 = (const float*)d_in[7];
    const float* W_rm2 = (const float*)d_in[8];
    const float* b_rm2 = (const float*)d_in[9];
    const float* W_rr  = (const float*)d_in[10];
    const float* b_rr  = (const float*)d_in[11];
    const float* W_rc  = (const float*)d_in[12];
    const float* b_rc  = (const float*)d_in[13];

    unsigned short* wf = (unsigned short*)d_ws;
    const int E = in_sizes[1];

    hipLaunchKernelGGL(prep_w, dim3(160), dim3(256), 0, stream,
                       W_rm1, W_rm2, W_rr, W_rc, wf);

    const int blocks = (E + 63) / 64;   // 64 edges per block (2 waves x 32)
    hipLaunchKernelGGL(arn_mfma, dim3(blocks), dim3(128), 0, stream,
                       known_mask, obs_idx, obs_mask_idx, attr_idx,
                       obs_embs, fea_corr,
                       b_rm1, b_rm2, b_rr, b_rc,
                       wf, (float*)d_out, E);
}

// Round 2
// 907.583 us; speedup vs baseline: 1.3035x; 1.0058x over previous
//
#include <hip/hip_runtime.h>
#include <math.h>

#define FDIM 64
#define HDIM 128

typedef __attribute__((ext_vector_type(8)))  short v8s;
typedef __attribute__((ext_vector_type(16))) float f32x16;

#define MFMA32(a,b,c) __builtin_amdgcn_mfma_f32_32x32x16_bf16(a,b,c,0,0,0)

// ---- fp32 -> bf16 hi/lo split helpers (hi = truncation, lo = round-half-up of exact remainder)
__device__ __forceinline__ unsigned short bf_hi(float v){
    return (unsigned short)(__float_as_uint(v) >> 16);
}
__device__ __forceinline__ float hi_part(float v){
    return __uint_as_float(__float_as_uint(v) & 0xFFFF0000u);
}
__device__ __forceinline__ unsigned short bf_rnd(float v){
    return (unsigned short)((__float_as_uint(v) + 0x8000u) >> 16);
}

// split 8 fp32 -> bf16 hi frag + lo frag (in registers)
__device__ __forceinline__ void split8(const float* x, v8s& ah, v8s& al){
    #pragma unroll
    for (int j = 0; j < 8; ++j){
        unsigned u = __float_as_uint(x[j]);
        ((unsigned short*)&ah)[j] = (unsigned short)(u >> 16);
        float rem = x[j] - __uint_as_float(u & 0xFFFF0000u);
        ((unsigned short*)&al)[j] = (unsigned short)((__float_as_uint(rem) + 0x8000u) >> 16);
    }
}

// ---- branchless gelu: 0.5x(1+erf(x/sqrt2)), erf via A&S 7.1.26 (|err|<1.5e-7), tail clamped at z=4
__device__ __forceinline__ float gelu_fast(float x){
    float z = fminf(fabsf(x) * 0.70710678118654752440f, 4.0f);
    float t = __builtin_amdgcn_rcpf(fmaf(0.3275911f, z, 1.0f));
    float p = fmaf(t, 1.061405429f, -1.453152027f);
    p = fmaf(t, p, 1.421413741f);
    p = fmaf(t, p, -0.284496736f);
    p = fmaf(t, p, 0.254829592f);
    float r  = t * p;
    float ez = __expf(-z * z);
    float erfv = fmaf(-r, ez, 1.0f);
    erfv = copysignf(erfv, x);
    float hx = 0.5f * x;
    return fmaf(hx, erfv, hx);
}

// =====================================================================================
// Prep kernel (unchanged): split W1..W4 into hi/lo bf16, MFMA B-fragment order.
// =====================================================================================
__global__ void prep_w(const float* __restrict__ W1, const float* __restrict__ W2,
                       const float* __restrict__ W3, const float* __restrict__ W4,
                       unsigned short* __restrict__ wf)
{
    int idx = blockIdx.x * 256 + threadIdx.x;
    if (idx >= 40960) return;
    const float* W; int N, KS, ub, local;
    if (idx < 8192)       { W = W1; N = HDIM; KS = 4; ub = 0;     local = idx;         }
    else if (idx < 16384) { W = W2; N = FDIM; KS = 8; ub = 16384; local = idx - 8192;  }
    else if (idx < 24576) { W = W3; N = HDIM; KS = 4; ub = 32768; local = idx - 16384; }
    else                  { W = W4; N = HDIM; KS = 8; ub = 49152; local = idx - 24576; }
    int tile   = local >> 9;
    int within = local & 511;
    int l = within >> 3, j = within & 7;
    int ks = tile % KS, nt = tile / KS;
    int k = ks * 16 + (l >> 5) * 8 + j;
    int n = nt * 32 + (l & 31);
    float v = W[k * N + n];
    float rem = v - hi_part(v);
    wf[ub + tile * 1024 +       l * 8 + j] = bf_hi(v);
    wf[ub + tile * 1024 + 512 + l * 8 + j] = bf_rnd(rem);
}

// =====================================================================================
// Main kernel: 1 wave = 1 block = 32 edges. Single 16KB fp32 activation buffer
// (bijective XOR swizzle), read-side hi/lo split, softmax after transpose (2-lane rows).
// =====================================================================================
__global__ __launch_bounds__(64, 3)
void arn_mfma(const float* __restrict__ known_mask,
              const int*   __restrict__ obs_idx,
              const int*   __restrict__ obs_mask_idx,
              const int*   __restrict__ attr_idx,
              const float* __restrict__ obs_embs,
              const float* __restrict__ fea_corr,
              const float* __restrict__ b_rm1, const float* __restrict__ b_rm2,
              const float* __restrict__ b_rr,  const float* __restrict__ b_rc,
              const unsigned short* __restrict__ wf,
              float* __restrict__ out, int E)
{
    __shared__ __align__(16) unsigned char smem[16384];
    const int lane = threadIdx.x;          // 0..63
    const int cl = lane & 31;
    const int hf = lane >> 5;
    const long long ebase = (long long)blockIdx.x * 32;

    // ---- per-edge indices in registers (lanes 32-63 hold duplicates)
    int attrv, mrowv, obsIv;
    {
        long long e = ebase + cl;
        int ec = (e < (long long)E) ? (int)e : (E - 1);
        attrv = attr_idx[ec];
        mrowv = obs_mask_idx[ec];
        obsIv = obs_idx[ec];
    }

    // ---- stage 0: raw masked mask-row -> LDS fp32 [32][64] (swizzled). No softmax here.
    #pragma unroll
    for (int r = 0; r < 32; ++r){
        int mrow = __shfl(mrowv, r);
        int attr = __shfl(attrv, r);
        float v = known_mask[(long long)mrow * FDIM + lane];
        v = (lane == attr) ? 0.f : v;
        *(float*)(smem + r * 256 + ((lane * 4) ^ ((r & 15) << 4))) = v;
    }

    // ---- GEMM1: softmax(S)[32,64] @ W_rm1 -> gelu -> h1 fp32 [32][128]
    {
        v8s ah[4], al[4];
        {
            float x[32];
            const int key = (cl & 15) << 4;
            #pragma unroll
            for (int ks = 0; ks < 4; ++ks){
                int g0 = ks * 64 + hf * 32;
                float4 a0 = *(const float4*)(smem + cl * 256 + (g0 ^ key));
                float4 a1 = *(const float4*)(smem + cl * 256 + ((g0 + 16) ^ key));
                x[ks*8+0]=a0.x; x[ks*8+1]=a0.y; x[ks*8+2]=a0.z; x[ks*8+3]=a0.w;
                x[ks*8+4]=a1.x; x[ks*8+5]=a1.y; x[ks*8+6]=a1.z; x[ks*8+7]=a1.w;
            }
            // row cl lives in lanes (cl, cl+32): in-lane reduce + one cross shuffle
            float mx = x[0];
            #pragma unroll
            for (int i = 1; i < 32; ++i) mx = fmaxf(mx, x[i]);
            mx = fmaxf(mx, __shfl_xor(mx, 32));
            float s = 0.f;
            #pragma unroll
            for (int i = 0; i < 32; ++i){ x[i] = __expf(x[i] - mx); s += x[i]; }
            s += __shfl_xor(s, 32);
            float rs = __builtin_amdgcn_rcpf(s);
            #pragma unroll
            for (int i = 0; i < 32; ++i) x[i] *= rs;
            #pragma unroll
            for (int ks = 0; ks < 4; ++ks) split8(&x[ks*8], ah[ks], al[ks]);
        }
        #pragma unroll
        for (int nt = 0; nt < 4; ++nt){
            float bias = b_rm1[nt * 32 + cl];
            f32x16 acc;
            #pragma unroll
            for (int i = 0; i < 16; ++i) acc[i] = bias;
            __builtin_amdgcn_s_setprio(1);
            #pragma unroll
            for (int ks = 0; ks < 4; ++ks){
                const v8s* wp = (const v8s*)(wf + (nt * 4 + ks) * 1024);
                v8s bh = wp[lane], bl = wp[lane + 64];
                acc = MFMA32(ah[ks], bh, acc);
                acc = MFMA32(ah[ks], bl, acc);
                acc = MFMA32(al[ks], bh, acc);
            }
            __builtin_amdgcn_s_setprio(0);
            #pragma unroll
            for (int g = 0; g < 16; ++g){
                int row = (g & 3) + 8 * (g >> 2) + 4 * hf;
                float y = gelu_fast(acc[g]);
                *(float*)(smem + row * 512 + ((nt * 128 + cl * 4) ^ ((row & 31) << 4))) = y;
            }
        }
    }

    // ---- GEMM2: h1[32,128] @ W_rm2 -> gelu -> * fea_corr[attr] -> t fp32 [32][64]
    {
        v8s ah[8], al[8];
        {
            const int key = (cl & 31) << 4;
            #pragma unroll
            for (int ks = 0; ks < 8; ++ks){
                int g0 = ks * 64 + hf * 32;
                float t[8];
                float4 a0 = *(const float4*)(smem + cl * 512 + (g0 ^ key));
                float4 a1 = *(const float4*)(smem + cl * 512 + ((g0 + 16) ^ key));
                t[0]=a0.x; t[1]=a0.y; t[2]=a0.z; t[3]=a0.w;
                t[4]=a1.x; t[5]=a1.y; t[6]=a1.z; t[7]=a1.w;
                split8(t, ah[ks], al[ks]);
            }
        }
        int ai[16];
        #pragma unroll
        for (int g = 0; g < 16; ++g) ai[g] = __shfl(attrv, (g & 3) + 8 * (g >> 2) + 4 * hf);
        #pragma unroll
        for (int nt = 0; nt < 2; ++nt){
            float fc[16];
            #pragma unroll
            for (int g = 0; g < 16; ++g) fc[g] = fea_corr[ai[g] * FDIM + nt * 32 + cl];
            float bias = b_rm2[nt * 32 + cl];
            f32x16 acc;
            #pragma unroll
            for (int i = 0; i < 16; ++i) acc[i] = bias;
            __builtin_amdgcn_s_setprio(1);
            #pragma unroll
            for (int ks = 0; ks < 8; ++ks){
                const v8s* wp = (const v8s*)(wf + 16384 + (nt * 8 + ks) * 1024);
                v8s bh = wp[lane], bl = wp[lane + 64];
                acc = MFMA32(ah[ks], bh, acc);
                acc = MFMA32(ah[ks], bl, acc);
                acc = MFMA32(al[ks], bh, acc);
            }
            __builtin_amdgcn_s_setprio(0);
            #pragma unroll
            for (int g = 0; g < 16; ++g){
                int row = (g & 3) + 8 * (g >> 2) + 4 * hf;
                float y = gelu_fast(acc[g]) * fc[g];
                *(float*)(smem + row * 256 + ((nt * 128 + cl * 4) ^ ((row & 15) << 4))) = y;
            }
        }
    }

    // ---- GEMM3: t[32,64] @ W_rr -> gelu -> * obs_h -> u fp32 [32][128]
    {
        v8s ah[4], al[4];
        {
            const int key = (cl & 15) << 4;
            #pragma unroll
            for (int ks = 0; ks < 4; ++ks){
                int g0 = ks * 64 + hf * 32;
                float t[8];
                float4 a0 = *(const float4*)(smem + cl * 256 + (g0 ^ key));
                float4 a1 = *(const float4*)(smem + cl * 256 + ((g0 + 16) ^ key));
                t[0]=a0.x; t[1]=a0.y; t[2]=a0.z; t[3]=a0.w;
                t[4]=a1.x; t[5]=a1.y; t[6]=a1.z; t[7]=a1.w;
                split8(t, ah[ks], al[ks]);
            }
        }
        int oi[16];
        #pragma unroll
        for (int g = 0; g < 16; ++g) oi[g] = __shfl(obsIv, (g & 3) + 8 * (g >> 2) + 4 * hf);
        float ob[2][16];
        #pragma unroll
        for (int g = 0; g < 16; ++g) ob[0][g] = obs_embs[(long long)oi[g] * HDIM + cl];
        #pragma unroll
        for (int nt = 0; nt < 4; ++nt){
            if (nt < 3){
                #pragma unroll
                for (int g = 0; g < 16; ++g)
                    ob[(nt + 1) & 1][g] = obs_embs[(long long)oi[g] * HDIM + (nt + 1) * 32 + cl];
            }
            float bias = b_rr[nt * 32 + cl];
            f32x16 acc;
            #pragma unroll
            for (int i = 0; i < 16; ++i) acc[i] = bias;
            __builtin_amdgcn_s_setprio(1);
            #pragma unroll
            for (int ks = 0; ks < 4; ++ks){
                const v8s* wp = (const v8s*)(wf + 32768 + (nt * 4 + ks) * 1024);
                v8s bh = wp[lane], bl = wp[lane + 64];
                acc = MFMA32(ah[ks], bh, acc);
                acc = MFMA32(ah[ks], bl, acc);
                acc = MFMA32(al[ks], bh, acc);
            }
            __builtin_amdgcn_s_setprio(0);
            #pragma unroll
            for (int g = 0; g < 16; ++g){
                int row = (g & 3) + 8 * (g >> 2) + 4 * hf;
                float y = ob[nt & 1][g] * gelu_fast(acc[g]);
                *(float*)(smem + row * 512 + ((nt * 128 + cl * 4) ^ ((row & 31) << 4))) = y;
            }
        }
    }

    // ---- GEMM4: u[32,128] @ W_rc -> gelu -> out
    {
        v8s ah[8], al[8];
        {
            const int key = (cl & 31) << 4;
            #pragma unroll
            for (int ks = 0; ks < 8; ++ks){
                int g0 = ks * 64 + hf * 32;
                float t[8];
                float4 a0 = *(const float4*)(smem + cl * 512 + (g0 ^ key));
                float4 a1 = *(const float4*)(smem + cl * 512 + ((g0 + 16) ^ key));
                t[0]=a0.x; t[1]=a0.y; t[2]=a0.z; t[3]=a0.w;
                t[4]=a1.x; t[5]=a1.y; t[6]=a1.z; t[7]=a1.w;
                split8(t, ah[ks], al[ks]);
            }
        }
        #pragma unroll
        for (int nt = 0; nt < 4; ++nt){
            float bias = b_rc[nt * 32 + cl];
            f32x16 acc;
            #pragma unroll
            for (int i = 0; i < 16; ++i) acc[i] = bias;
            __builtin_amdgcn_s_setprio(1);
            #pragma unroll
            for (int ks = 0; ks < 8; ++ks){
                const v8s* wp = (const v8s*)(wf + 49152 + (nt * 8 + ks) * 1024);
                v8s bh = wp[lane], bl = wp[lane + 64];
                acc = MFMA32(ah[ks], bh, acc);
                acc = MFMA32(ah[ks], bl, acc);
                acc = MFMA32(al[ks], bh, acc);
            }
            __builtin_amdgcn_s_setprio(0);
            #pragma unroll
            for (int g = 0; g < 16; ++g){
                int row = (g & 3) + 8 * (g >> 2) + 4 * hf;
                long long e = ebase + row;
                if (e < (long long)E)
                    out[e * HDIM + nt * 32 + cl] = gelu_fast(acc[g]);
            }
        }
    }
}

extern "C" void kernel_launch(void* const* d_in, const int* in_sizes, int n_in,
                              void* d_out, int out_size, void* d_ws, size_t ws_size,
                              hipStream_t stream)
{
    (void)n_in; (void)out_size; (void)ws_size;   // requires ws_size >= 163840 B
    const float* known_mask   = (const float*)d_in[0];
    const int*   obs_idx      = (const int*)d_in[1];
    const int*   obs_mask_idx = (const int*)d_in[2];
    const int*   attr_idx     = (const int*)d_in[3];
    const float* obs_embs     = (const float*)d_in[4];
    const float* fea_corr     = (const float*)d_in[5];
    const float* W_rm1 = (const float*)d_in[6];
    const float* b_rm1 = (const float*)d_in[7];
    const float* W_rm2 = (const float*)d_in[8];
    const float* b_rm2 = (const float*)d_in[9];
    const float* W_rr  = (const float*)d_in[10];
    const float* b_rr  = (const float*)d_in[11];
    const float* W_rc  = (const float*)d_in[12];
    const float* b_rc  = (const float*)d_in[13];

    unsigned short* wf = (unsigned short*)d_ws;
    const int E = in_sizes[1];

    hipLaunchKernelGGL(prep_w, dim3(160), dim3(256), 0, stream,
                       W_rm1, W_rm2, W_rr, W_rc, wf);

    const int blocks = (E + 31) / 32;   // 32 edges per 1-wave block
    hipLaunchKernelGGL(arn_mfma, dim3(blocks), dim3(64), 0, stream,
                       known_mask, obs_idx, obs_mask_idx, attr_idx,
                       obs_embs, fea_corr,
                       b_rm1, b_rm2, b_rr, b_rc,
                       wf, (float*)d_out, E);
}

// Round 3
// 622.338 us; speedup vs baseline: 1.9009x; 1.4583x over previous
//
#include <hip/hip_runtime.h>
#include <math.h>

#define FDIM 64
#define HDIM 128

typedef __attribute__((ext_vector_type(8)))  short v8s;
typedef __attribute__((ext_vector_type(16))) float f32x16;

#define MFMA32(a,b,c) __builtin_amdgcn_mfma_f32_32x32x16_bf16(a,b,c,0,0,0)

// ---- fp32 -> bf16 hi/lo split helpers
__device__ __forceinline__ unsigned short bf_hi(float v){
    return (unsigned short)(__float_as_uint(v) >> 16);
}
__device__ __forceinline__ float hi_part(float v){
    return __uint_as_float(__float_as_uint(v) & 0xFFFF0000u);
}
__device__ __forceinline__ unsigned short bf_rnd(float v){
    return (unsigned short)((__float_as_uint(v) + 0x8000u) >> 16);
}

// split 8 fp32 -> bf16 hi frag + lo frag (in registers)
__device__ __forceinline__ void split8(const float* x, v8s& ah, v8s& al){
    #pragma unroll
    for (int j = 0; j < 8; ++j){
        unsigned u = __float_as_uint(x[j]);
        ((unsigned short*)&ah)[j] = (unsigned short)(u >> 16);
        float rem = x[j] - __uint_as_float(u & 0xFFFF0000u);
        ((unsigned short*)&al)[j] = (unsigned short)((__float_as_uint(rem) + 0x8000u) >> 16);
    }
}

// ---- branchless gelu: 0.5x(1+erf(x/sqrt2)), erf via A&S 7.1.26 (|err|<1.5e-7)
__device__ __forceinline__ float gelu_fast(float x){
    float z = fminf(fabsf(x) * 0.70710678118654752440f, 4.0f);
    float t = __builtin_amdgcn_rcpf(fmaf(0.3275911f, z, 1.0f));
    float p = fmaf(t, 1.061405429f, -1.453152027f);
    p = fmaf(t, p, 1.421413741f);
    p = fmaf(t, p, -0.284496736f);
    p = fmaf(t, p, 0.254829592f);
    float r  = t * p;
    float ez = __expf(-z * z);
    float erfv = fmaf(-r, ez, 1.0f);
    erfv = copysignf(erfv, x);
    float hx = 0.5f * x;
    return fmaf(hx, erfv, hx);
}

// =====================================================================================
// Prep kernel (unchanged): split W1..W4 into hi/lo bf16, MFMA B-fragment order.
// =====================================================================================
__global__ void prep_w(const float* __restrict__ W1, const float* __restrict__ W2,
                       const float* __restrict__ W3, const float* __restrict__ W4,
                       unsigned short* __restrict__ wf)
{
    int idx = blockIdx.x * 256 + threadIdx.x;
    if (idx >= 40960) return;
    const float* W; int N, KS, ub, local;
    if (idx < 8192)       { W = W1; N = HDIM; KS = 4; ub = 0;     local = idx;         }
    else if (idx < 16384) { W = W2; N = FDIM; KS = 8; ub = 16384; local = idx - 8192;  }
    else if (idx < 24576) { W = W3; N = HDIM; KS = 4; ub = 32768; local = idx - 16384; }
    else                  { W = W4; N = HDIM; KS = 8; ub = 49152; local = idx - 24576; }
    int tile   = local >> 9;
    int within = local & 511;
    int l = within >> 3, j = within & 7;
    int ks = tile % KS, nt = tile / KS;
    int k = ks * 16 + (l >> 5) * 8 + j;
    int n = nt * 32 + (l & 31);
    float v = W[k * N + n];
    float rem = v - hi_part(v);
    wf[ub + tile * 1024 +       l * 8 + j] = bf_hi(v);
    wf[ub + tile * 1024 + 512 + l * 8 + j] = bf_rnd(rem);
}

// =====================================================================================
// Main kernel: 1 wave = 1 block = 32 edges. Single 16KB fp32 activation buffer
// (bijective XOR swizzle), read-side hi/lo split. fea_corr folded into GEMM3 A-read,
// obs_embs folded into GEMM4 A-read (lane == row, so per-lane contiguous loads).
// =====================================================================================
__global__ __launch_bounds__(64, 2)
void arn_mfma(const float* __restrict__ known_mask,
              const int*   __restrict__ obs_idx,
              const int*   __restrict__ obs_mask_idx,
              const int*   __restrict__ attr_idx,
              const float* __restrict__ obs_embs,
              const float* __restrict__ fea_corr,
              const float* __restrict__ b_rm1, const float* __restrict__ b_rm2,
              const float* __restrict__ b_rr,  const float* __restrict__ b_rc,
              const unsigned short* __restrict__ wf,
              float* __restrict__ out, int E)
{
    __shared__ __align__(16) unsigned char smem[16384];
    const int lane = threadIdx.x;          // 0..63
    const int cl = lane & 31;
    const int hf = lane >> 5;
    const long long ebase = (long long)blockIdx.x * 32;

    // ---- per-edge indices in registers: lane l holds indices of edge (ebase + cl) == its A-row
    int attrv, mrowv, obsIv;
    {
        long long e = ebase + cl;
        int ec = (e < (long long)E) ? (int)e : (E - 1);
        attrv = attr_idx[ec];
        mrowv = obs_mask_idx[ec];
        obsIv = obs_idx[ec];
    }

    // ---- stage 0: raw masked mask-row -> LDS fp32 [32][64] (swizzled)
    #pragma unroll
    for (int r = 0; r < 32; ++r){
        int mrow = __shfl(mrowv, r);
        int attr = __shfl(attrv, r);
        float v = known_mask[(long long)mrow * FDIM + lane];
        v = (lane == attr) ? 0.f : v;
        *(float*)(smem + r * 256 + ((lane * 4) ^ ((r & 15) << 4))) = v;
    }

    // ---- GEMM1: softmax(S)[32,64] @ W_rm1 -> gelu -> h1 fp32 [32][128]
    {
        v8s ah[4], al[4];
        {
            float x[32];
            const int key = (cl & 15) << 4;
            #pragma unroll
            for (int ks = 0; ks < 4; ++ks){
                int g0 = ks * 64 + hf * 32;
                float4 a0 = *(const float4*)(smem + cl * 256 + (g0 ^ key));
                float4 a1 = *(const float4*)(smem + cl * 256 + ((g0 + 16) ^ key));
                x[ks*8+0]=a0.x; x[ks*8+1]=a0.y; x[ks*8+2]=a0.z; x[ks*8+3]=a0.w;
                x[ks*8+4]=a1.x; x[ks*8+5]=a1.y; x[ks*8+6]=a1.z; x[ks*8+7]=a1.w;
            }
            // row cl lives in lanes (cl, cl+32): in-lane reduce + one cross shuffle
            float mx = x[0];
            #pragma unroll
            for (int i = 1; i < 32; ++i) mx = fmaxf(mx, x[i]);
            mx = fmaxf(mx, __shfl_xor(mx, 32));
            float s = 0.f;
            #pragma unroll
            for (int i = 0; i < 32; ++i){ x[i] = __expf(x[i] - mx); s += x[i]; }
            s += __shfl_xor(s, 32);
            float rs = __builtin_amdgcn_rcpf(s);
            #pragma unroll
            for (int i = 0; i < 32; ++i) x[i] *= rs;
            #pragma unroll
            for (int ks = 0; ks < 4; ++ks) split8(&x[ks*8], ah[ks], al[ks]);
        }
        #pragma unroll
        for (int nt = 0; nt < 4; ++nt){
            float bias = b_rm1[nt * 32 + cl];
            f32x16 acc;
            #pragma unroll
            for (int i = 0; i < 16; ++i) acc[i] = bias;
            __builtin_amdgcn_s_setprio(1);
            #pragma unroll
            for (int ks = 0; ks < 4; ++ks){
                const v8s* wp = (const v8s*)(wf + (nt * 4 + ks) * 1024);
                v8s bh = wp[lane], bl = wp[lane + 64];
                acc = MFMA32(ah[ks], bh, acc);
                acc = MFMA32(ah[ks], bl, acc);
                acc = MFMA32(al[ks], bh, acc);
            }
            __builtin_amdgcn_s_setprio(0);
            #pragma unroll
            for (int g = 0; g < 16; ++g){
                int row = (g & 3) + 8 * (g >> 2) + 4 * hf;
                float y = gelu_fast(acc[g]);
                *(float*)(smem + row * 512 + ((nt * 128 + cl * 4) ^ ((row & 31) << 4))) = y;
            }
        }
    }

    // ---- GEMM2: h1[32,128] @ W_rm2 -> gelu -> t fp32 [32][64] (fea_corr deferred to GEMM3)
    {
        v8s ah[8], al[8];
        {
            const int key = (cl & 31) << 4;
            #pragma unroll
            for (int ks = 0; ks < 8; ++ks){
                int g0 = ks * 64 + hf * 32;
                float t[8];
                float4 a0 = *(const float4*)(smem + cl * 512 + (g0 ^ key));
                float4 a1 = *(const float4*)(smem + cl * 512 + ((g0 + 16) ^ key));
                t[0]=a0.x; t[1]=a0.y; t[2]=a0.z; t[3]=a0.w;
                t[4]=a1.x; t[5]=a1.y; t[6]=a1.z; t[7]=a1.w;
                split8(t, ah[ks], al[ks]);
            }
        }
        #pragma unroll
        for (int nt = 0; nt < 2; ++nt){
            float bias = b_rm2[nt * 32 + cl];
            f32x16 acc;
            #pragma unroll
            for (int i = 0; i < 16; ++i) acc[i] = bias;
            __builtin_amdgcn_s_setprio(1);
            #pragma unroll
            for (int ks = 0; ks < 8; ++ks){
                const v8s* wp = (const v8s*)(wf + 16384 + (nt * 8 + ks) * 1024);
                v8s bh = wp[lane], bl = wp[lane + 64];
                acc = MFMA32(ah[ks], bh, acc);
                acc = MFMA32(ah[ks], bl, acc);
                acc = MFMA32(al[ks], bh, acc);
            }
            __builtin_amdgcn_s_setprio(0);
            #pragma unroll
            for (int g = 0; g < 16; ++g){
                int row = (g & 3) + 8 * (g >> 2) + 4 * hf;
                float y = gelu_fast(acc[g]);
                *(float*)(smem + row * 256 + ((nt * 128 + cl * 4) ^ ((row & 15) << 4))) = y;
            }
        }
    }

    // ---- GEMM3: (t * fea_corr[attr])[32,64] @ W_rr -> gelu -> u fp32 [32][128]
    //      (obs_embs multiply deferred to GEMM4 A-read)
    {
        v8s ah[4], al[4];
        {
            const int key = (cl & 15) << 4;
            const float* fcrow = fea_corr + (long long)attrv * FDIM;  // lane's own row
            #pragma unroll
            for (int ks = 0; ks < 4; ++ks){
                int g0 = ks * 64 + hf * 32;                 // byte offset of k-start
                int kf = ks * 16 + hf * 8;                  // float index of k-start
                float4 a0 = *(const float4*)(smem + cl * 256 + (g0 ^ key));
                float4 a1 = *(const float4*)(smem + cl * 256 + ((g0 + 16) ^ key));
                float4 f0 = *(const float4*)(fcrow + kf);
                float4 f1 = *(const float4*)(fcrow + kf + 4);
                float t[8];
                t[0]=a0.x*f0.x; t[1]=a0.y*f0.y; t[2]=a0.z*f0.z; t[3]=a0.w*f0.w;
                t[4]=a1.x*f1.x; t[5]=a1.y*f1.y; t[6]=a1.z*f1.z; t[7]=a1.w*f1.w;
                split8(t, ah[ks], al[ks]);
            }
        }
        #pragma unroll
        for (int nt = 0; nt < 4; ++nt){
            float bias = b_rr[nt * 32 + cl];
            f32x16 acc;
            #pragma unroll
            for (int i = 0; i < 16; ++i) acc[i] = bias;
            __builtin_amdgcn_s_setprio(1);
            #pragma unroll
            for (int ks = 0; ks < 4; ++ks){
                const v8s* wp = (const v8s*)(wf + 32768 + (nt * 4 + ks) * 1024);
                v8s bh = wp[lane], bl = wp[lane + 64];
                acc = MFMA32(ah[ks], bh, acc);
                acc = MFMA32(ah[ks], bl, acc);
                acc = MFMA32(al[ks], bh, acc);
            }
            __builtin_amdgcn_s_setprio(0);
            #pragma unroll
            for (int g = 0; g < 16; ++g){
                int row = (g & 3) + 8 * (g >> 2) + 4 * hf;
                float y = gelu_fast(acc[g]);
                *(float*)(smem + row * 512 + ((nt * 128 + cl * 4) ^ ((row & 31) << 4))) = y;
            }
        }
    }

    // ---- GEMM4: (u * obs_h)[32,128] @ W_rc -> gelu -> out
    {
        v8s ah[8], al[8];
        {
            const int key = (cl & 31) << 4;
            const float* obrow = obs_embs + (long long)obsIv * HDIM;  // lane's own row
            #pragma unroll
            for (int ks = 0; ks < 8; ++ks){
                int g0 = ks * 64 + hf * 32;
                int kf = ks * 16 + hf * 8;
                float4 a0 = *(const float4*)(smem + cl * 512 + (g0 ^ key));
                float4 a1 = *(const float4*)(smem + cl * 512 + ((g0 + 16) ^ key));
                float4 o0 = *(const float4*)(obrow + kf);
                float4 o1 = *(const float4*)(obrow + kf + 4);
                float t[8];
                t[0]=a0.x*o0.x; t[1]=a0.y*o0.y; t[2]=a0.z*o0.z; t[3]=a0.w*o0.w;
                t[4]=a1.x*o1.x; t[5]=a1.y*o1.y; t[6]=a1.z*o1.z; t[7]=a1.w*o1.w;
                split8(t, ah[ks], al[ks]);
            }
        }
        #pragma unroll
        for (int nt = 0; nt < 4; ++nt){
            float bias = b_rc[nt * 32 + cl];
            f32x16 acc;
            #pragma unroll
            for (int i = 0; i < 16; ++i) acc[i] = bias;
            __builtin_amdgcn_s_setprio(1);
            #pragma unroll
            for (int ks = 0; ks < 8; ++ks){
                const v8s* wp = (const v8s*)(wf + 49152 + (nt * 8 + ks) * 1024);
                v8s bh = wp[lane], bl = wp[lane + 64];
                acc = MFMA32(ah[ks], bh, acc);
                acc = MFMA32(ah[ks], bl, acc);
                acc = MFMA32(al[ks], bh, acc);
            }
            __builtin_amdgcn_s_setprio(0);
            #pragma unroll
            for (int g = 0; g < 16; ++g){
                int row = (g & 3) + 8 * (g >> 2) + 4 * hf;
                long long e = ebase + row;
                if (e < (long long)E)
                    out[e * HDIM + nt * 32 + cl] = gelu_fast(acc[g]);
            }
        }
    }
}

extern "C" void kernel_launch(void* const* d_in, const int* in_sizes, int n_in,
                              void* d_out, int out_size, void* d_ws, size_t ws_size,
                              hipStream_t stream)
{
    (void)n_in; (void)out_size; (void)ws_size;   // requires ws_size >= 163840 B
    const float* known_mask   = (const float*)d_in[0];
    const int*   obs_idx      = (const int*)d_in[1];
    const int*   obs_mask_idx = (const int*)d_in[2];
    const int*   attr_idx     = (const int*)d_in[3];
    const float* obs_embs     = (const float*)d_in[4];
    const float* fea_corr     = (const float*)d_in[5];
    const float* W_rm1 = (const float*)d_in[6];
    const float* b_rm1 = (const float*)d_in[7];
    const float* W_rm2 = (const float*)d_in[8];
    const float* b_rm2 = (const float*)d_in[9];
    const float* W_rr  = (const float*)d_in[10];
    const float* b_rr  = (const float*)d_in[11];
    const float* W_rc  = (const float*)d_in[12];
    const float* b_rc  = (const float*)d_in[13];

    unsigned short* wf = (unsigned short*)d_ws;
    const int E = in_sizes[1];

    hipLaunchKernelGGL(prep_w, dim3(160), dim3(256), 0, stream,
                       W_rm1, W_rm2, W_rr, W_rc, wf);

    const int blocks = (E + 31) / 32;   // 32 edges per 1-wave block
    hipLaunchKernelGGL(arn_mfma, dim3(blocks), dim3(64), 0, stream,
                       known_mask, obs_idx, obs_mask_idx, attr_idx,
                       obs_embs, fea_corr,
                       b_rm1, b_rm2, b_rr, b_rc,
                       wf, (float*)d_out, E);
}